// Round 7
// baseline (274.103 us; speedup 1.0000x reference)
//
#include <hip/hip_runtime.h>
#include <stdint.h>
#include <math.h>

#define S_LEN 2048
#define DIM   64
#define QBLK  128
#define KVBLK 64
#define NKV   (S_LEN / KVBLK)   // 32

typedef __attribute__((ext_vector_type(8))) short short8;
typedef __attribute__((ext_vector_type(4))) float f32x4;

// fp32 -> bf16 round-to-nearest-even (cold paths only)
static __device__ __forceinline__ unsigned short f2bf(float f) {
    union { float f; uint32_t u; } cv; cv.f = f;
    uint32_t u = cv.u;
    return (unsigned short)((u + 0x7fffu + ((u >> 16) & 1u)) >> 16);
}

// async global->LDS, 16B per lane, LDS dest = wave-uniform base + lane*16
static __device__ __forceinline__ void gload16(const void* g, void* l) {
    __builtin_amdgcn_global_load_lds(
        (const __attribute__((address_space(1))) unsigned int*)g,
        (__attribute__((address_space(3))) unsigned int*)l, 16, 0, 0);
}

static __device__ __forceinline__ float vmax3(float a, float b, float c) {
    float d;
    asm("v_max3_f32 %0, %1, %2, %3" : "=v"(d) : "v"(a), "v"(b), "v"(c));
    return d;
}

// ---------------- pre-kernel 1: K fp32 -> bf16, per-row 16B-chunk XOR swizzle ----------------
__global__ void cvt_k(const float* __restrict__ kp, unsigned short* __restrict__ kws) {
    const int idx = blockIdx.x * 256 + threadIdx.x;
    const int c   = idx & 7;
    const int s   = (idx >> 3) & (S_LEN - 1);
    const int bh  = idx >> 14;
    const float* src = kp + ((size_t)bh * S_LEN + s) * DIM + c * 8;
    const f32x4 a = *reinterpret_cast<const f32x4*>(src);
    const f32x4 b = *reinterpret_cast<const f32x4*>(src + 4);
    short8 t;
    t[0] = (short)f2bf(a[0]); t[1] = (short)f2bf(a[1]);
    t[2] = (short)f2bf(a[2]); t[3] = (short)f2bf(a[3]);
    t[4] = (short)f2bf(b[0]); t[5] = (short)f2bf(b[1]);
    t[6] = (short)f2bf(b[2]); t[7] = (short)f2bf(b[3]);
    unsigned short* dst = kws + ((size_t)bh * S_LEN + s) * DIM + (size_t)((c ^ (s & 7)) * 8);
    *reinterpret_cast<short8*>(dst) = t;
}

// ---------------- pre-kernel 2: V fp32 -> bf16 transposed [d][key-position], kappa-permuted ----
// Position p holds key kappa(p) = 32*p5 + 8*p4 + 4*p3 + 16*p2 + 2*p1 + p0, so the PV B-frag
// (lane-local, phi-mapped P) and A-frag (V^T) agree on key order. Chunk-XOR-swizzled like K.
__global__ void cvt_v(const float* __restrict__ vp, unsigned short* __restrict__ vtws) {
    const int bh = blockIdx.x >> 5;
    const int t  = blockIdx.x & 31;
    const int tid = threadIdx.x;
    __shared__ unsigned short ldsT[DIM][72];   // [d][local key]

    const int i = tid >> 2;
    const int dbase = (tid & 3) * 16;
    const float* src = vp + ((size_t)bh * S_LEN + t * 64 + i) * DIM + dbase;
#pragma unroll
    for (int q4 = 0; q4 < 4; ++q4) {
        const f32x4 a = *reinterpret_cast<const f32x4*>(src + q4 * 4);
#pragma unroll
        for (int j = 0; j < 4; ++j) ldsT[dbase + q4 * 4 + j][i] = f2bf(a[j]);
    }
    __syncthreads();
#pragma unroll
    for (int hh = 0; hh < 2; ++hh) {
        const int slot = tid + hh * 256;
        const int d = slot >> 3, c_st = slot & 7;
        const int cl = c_st ^ (d & 7);
        short8 t8;
#pragma unroll
        for (int j = 0; j < 8; ++j) {
            const int p = cl * 8 + j;
            const int kap = (p & 32) | ((p & 16) >> 1) | ((p & 8) >> 1) | ((p & 4) << 2) | (p & 3);
            t8[j] = (short)ldsT[d][kap];
        }
        unsigned short* dst = vtws + ((size_t)bh * DIM + d) * S_LEN + t * 64 + c_st * 8;
        *reinterpret_cast<short8*>(dst) = t8;
    }
}

// ---------------- main attention kernel: T15 pipeline QK(t) || SM(t-1)+PV(t-1) ----------------
__global__ __launch_bounds__(256, 4)
void attn_fwd(const float* __restrict__ qp, const unsigned short* __restrict__ kws,
              const unsigned short* __restrict__ vtws, float* __restrict__ op) {
    const int lb = (blockIdx.x & 7) * 128 + (blockIdx.x >> 3);   // XCD swizzle (bijective)
    const int bh = lb >> 4;
    const int qb = lb & 15;
    const int tid  = threadIdx.x;
    const int wave = tid >> 6;
    const int lane = tid & 63;
    const int g = lane >> 4;
    const int r = lane & 15;

    __shared__ unsigned short klds[2][KVBLK * DIM];   // [key][chunk-swz] 8KB x2
    __shared__ unsigned short vlds[2][DIM * KVBLK];   // [d][pos-swz]     8KB x2

    const float*          qg    = qp   + (size_t)bh * (S_LEN * DIM);
    const unsigned short* kbase = kws  + (size_t)bh * (S_LEN * DIM);
    const unsigned short* vbase = vtws + (size_t)bh * (S_LEN * DIM);
    float*                og    = op   + (size_t)bh * (S_LEN * DIM);

    // Q frags (B-operand: col=q=lane&15, k=8g+i), pre-scaled by 0.125*log2(e) (base-2 scores)
    const float qscale = 0.125f * 1.44269504088896340736f;
    const int q0 = qb * QBLK + wave * 32;
    short8 qfrag[2][2];
#pragma unroll
    for (int mt = 0; mt < 2; ++mt) {
        const float* qrow = qg + (size_t)(q0 + mt * 16 + r) * DIM;
#pragma unroll
        for (int ks = 0; ks < 2; ++ks) {
            const f32x4 a = *reinterpret_cast<const f32x4*>(qrow + ks * 32 + 8 * g);
            const f32x4 b = *reinterpret_cast<const f32x4*>(qrow + ks * 32 + 8 * g + 4);
            short8 t;
            t[0] = (short)f2bf(a[0] * qscale); t[1] = (short)f2bf(a[1] * qscale);
            t[2] = (short)f2bf(a[2] * qscale); t[3] = (short)f2bf(a[3] * qscale);
            t[4] = (short)f2bf(b[0] * qscale); t[5] = (short)f2bf(b[1] * qscale);
            t[6] = (short)f2bf(b[2] * qscale); t[7] = (short)f2bf(b[3] * qscale);
            qfrag[mt][ks] = t;
        }
    }

    // hoisted LDS fragment offsets (identical formula for klds and vlds)
    int off[4][2];
#pragma unroll
    for (int nt = 0; nt < 4; ++nt)
#pragma unroll
        for (int ks = 0; ks < 2; ++ks)
            off[nt][ks] = (nt * 16 + r) * DIM + (((ks << 2) | g) ^ (r & 7)) * 8;

    // O^T accumulators + lane-uniform m,l per mt
    f32x4 o[2][4];
    float m_run[2], l_part[2];
#pragma unroll
    for (int mt = 0; mt < 2; ++mt) {
#pragma unroll
        for (int nt = 0; nt < 4; ++nt) { f32x4 z = {0.f, 0.f, 0.f, 0.f}; o[mt][nt] = z; }
        m_run[mt] = -INFINITY; l_part[mt] = 0.0f;
    }

    const int srow = lane >> 3, schk = lane & 7;
    auto stageK = [&](int t, int buf) {
        const int kv0 = t * KVBLK;
#pragma unroll
        for (int h = 0; h < 2; ++h) {
            const int row = wave * 16 + h * 8;
            gload16(kbase + (size_t)(kv0 + row + srow) * DIM + schk * 8,
                    &klds[buf][row * DIM]);
        }
    };
    auto stageV = [&](int t, int buf) {
        const int kv0 = t * KVBLK;
#pragma unroll
        for (int h = 0; h < 2; ++h) {
            const int row = wave * 16 + h * 8;
            gload16(vbase + (size_t)(row + srow) * S_LEN + kv0 + schk * 8,
                    &vlds[buf][row * DIM]);
        }
    };

    const f32x4 z4 = {0.f, 0.f, 0.f, 0.f};

    // QK(t): stC = K(tile) * Q^T from klds[kbuf]  (16 MFMA, no barrier deps inside)
    auto qk = [&](f32x4 (&stC)[2][4], const unsigned short* kl) {
#pragma unroll
        for (int nt = 0; nt < 4; ++nt) {
            const short8 kf0 = *reinterpret_cast<const short8*>(kl + off[nt][0]);
            const short8 kf1 = *reinterpret_cast<const short8*>(kl + off[nt][1]);
            stC[0][nt] = __builtin_amdgcn_mfma_f32_16x16x32_bf16(kf0, qfrag[0][0], z4, 0, 0, 0);
            stC[1][nt] = __builtin_amdgcn_mfma_f32_16x16x32_bf16(kf0, qfrag[1][0], z4, 0, 0, 0);
            stC[0][nt] = __builtin_amdgcn_mfma_f32_16x16x32_bf16(kf1, qfrag[0][1], stC[0][nt], 0, 0, 0);
            stC[1][nt] = __builtin_amdgcn_mfma_f32_16x16x32_bf16(kf1, qfrag[1][1], stC[1][nt], 0, 0, 0);
        }
    };

    // SM(prev)+PV(prev): softmax on stP (register-only; overlaps qk's MFMAs), PV from vlds[vbuf]
    auto smpv = [&](f32x4 (&stP)[2][4], const unsigned short* vl) {
#pragma unroll
        for (int mt = 0; mt < 2; ++mt) {
            const f32x4 s0 = stP[mt][0], s1 = stP[mt][1], s2 = stP[mt][2], s3 = stP[mt][3];
            const float a0 = vmax3(s0[0], s0[1], s0[2]);
            const float a1 = vmax3(s0[3], s1[0], s1[1]);
            const float a2 = vmax3(s1[2], s1[3], s2[0]);
            const float a3 = vmax3(s2[1], s2[2], s2[3]);
            const float a4 = vmax3(s3[0], s3[1], s3[2]);
            const float lane_mx = fmaxf(vmax3(a0, a1, a2), vmax3(a3, a4, s3[3]));
            // defer-max (THR=8): rescale only when some lane's max outgrew m_run (wave-uniform)
            if (__any(lane_mx > m_run[mt] + 8.0f)) {
                float mx = fmaxf(lane_mx, __shfl_xor(lane_mx, 16));
                mx = fmaxf(mx, __shfl_xor(mx, 32));
                const float mnew = fmaxf(m_run[mt], mx);
                const float al = __builtin_amdgcn_exp2f(m_run[mt] - mnew);  // -inf -> 0 on 1st tile
                m_run[mt] = mnew;
                l_part[mt] *= al;
#pragma unroll
                for (int nt = 0; nt < 4; ++nt) {
                    f32x4 tt = o[mt][nt];
                    tt[0] *= al; tt[1] *= al; tt[2] *= al; tt[3] *= al;
                    o[mt][nt] = tt;
                }
            }
            const float mnow = m_run[mt];
            f32x4 p[4];
#pragma unroll
            for (int nt = 0; nt < 4; ++nt) {
                p[nt][0] = __builtin_amdgcn_exp2f(stP[mt][nt][0] - mnow);
                p[nt][1] = __builtin_amdgcn_exp2f(stP[mt][nt][1] - mnow);
                p[nt][2] = __builtin_amdgcn_exp2f(stP[mt][nt][2] - mnow);
                p[nt][3] = __builtin_amdgcn_exp2f(stP[mt][nt][3] - mnow);
            }
            l_part[mt] += ((p[0][0] + p[0][1]) + (p[0][2] + p[0][3]))
                        + ((p[1][0] + p[1][1]) + (p[1][2] + p[1][3]))
                        + ((p[2][0] + p[2][1]) + (p[2][2] + p[2][3]))
                        + ((p[3][0] + p[3][1]) + (p[3][2] + p[3][3]));
            short8 pfrag[2];
#pragma unroll
            for (int ks = 0; ks < 2; ++ks) {
                union { uint32_t u[4]; short8 v; } fr;
                asm("v_cvt_pk_bf16_f32 %0, %1, %2" : "=v"(fr.u[0])
                    : "v"(p[2*ks][0]),   "v"(p[2*ks][1]));
                asm("v_cvt_pk_bf16_f32 %0, %1, %2" : "=v"(fr.u[1])
                    : "v"(p[2*ks][2]),   "v"(p[2*ks][3]));
                asm("v_cvt_pk_bf16_f32 %0, %1, %2" : "=v"(fr.u[2])
                    : "v"(p[2*ks+1][0]), "v"(p[2*ks+1][1]));
                asm("v_cvt_pk_bf16_f32 %0, %1, %2" : "=v"(fr.u[3])
                    : "v"(p[2*ks+1][2]), "v"(p[2*ks+1][3]));
                pfrag[ks] = fr.v;
            }
            __builtin_amdgcn_s_setprio(1);
#pragma unroll
            for (int ntd = 0; ntd < 4; ++ntd) {
                const short8 vf0 = *reinterpret_cast<const short8*>(vl + off[ntd][0]);
                const short8 vf1 = *reinterpret_cast<const short8*>(vl + off[ntd][1]);
                o[mt][ntd] = __builtin_amdgcn_mfma_f32_16x16x32_bf16(vf0, pfrag[0], o[mt][ntd], 0, 0, 0);
                o[mt][ntd] = __builtin_amdgcn_mfma_f32_16x16x32_bf16(vf1, pfrag[1], o[mt][ntd], 0, 0, 0);
            }
            __builtin_amdgcn_s_setprio(0);
        }
    };

    // score double-state: even tiles -> stA, odd tiles -> stB (statically named; rule #20)
    f32x4 stA[2][4], stB[2][4];

    // ---- prologue: K(0),V(0) -> buf0; QK(0)->stA; K(1)->k1 in flight ----
    stageK(0, 0); stageV(0, 0);
    __syncthreads();
    stageK(1, 1);
    qk(stA, &klds[0][0]);
    __syncthreads();   // drains K(1)

    // ---- main loop, 2-unrolled: odd t {k1,v0,stB<-QK, SM/PV on stA}, even t {k0,v1,stA, stB} ----
    for (int tt = 1; tt < NKV; tt += 2) {
        {   // t = tt (odd): K(t) in klds[1]; V(t-1) in vlds[0]
            const int t = tt;
            if (t + 1 < NKV) stageK(t + 1, 0);   // overwrites K(t-1): QK(t-1) done pre-barrier
            stageV(t, 1);                        // overwrites V(t-2): PV(t-2) done pre-barrier
            qk(stB, &klds[1][0]);                // MFMA, independent of stA
            smpv(stA, &vlds[0][0]);              // SM(t-1) VALU overlaps qk; PV(t-1)
            __syncthreads();                     // drains stages; frees vlds[0], klds[1]
        }
        if (tt + 1 < NKV) {   // t = tt+1 (even): K(t) in klds[0]; V(t-1) in vlds[1]
            const int t = tt + 1;
            stageK(t + 1, 1);                    // t+1 <= NKV-1 here (tt <= NKV-3)
            stageV(t, 0);
            qk(stA, &klds[0][0]);
            smpv(stB, &vlds[1][0]);
            __syncthreads();
        }
    }
    // ---- epilogue: last tile NKV-1 (odd) -> stB, V(NKV-1) in vlds[1] ----
    smpv(stB, &vlds[1][0]);

#pragma unroll
    for (int mt = 0; mt < 2; ++mt) {
        float lfull = l_part[mt];
        lfull += __shfl_xor(lfull, 16);
        lfull += __shfl_xor(lfull, 32);
        const float inv = 1.0f / lfull;
        float* dst = og + (size_t)(q0 + mt * 16 + r) * DIM + 4 * g;
#pragma unroll
        for (int ntd = 0; ntd < 4; ++ntd) {
            f32x4 tt = o[mt][ntd];
            tt[0] *= inv; tt[1] *= inv; tt[2] *= inv; tt[3] *= inv;
            *reinterpret_cast<f32x4*>(dst + ntd * 16) = tt;
        }
    }
}

extern "C" void kernel_launch(void* const* d_in, const int* in_sizes, int n_in,
                              void* d_out, int out_size, void* d_ws, size_t ws_size,
                              hipStream_t stream) {
    const float* q = (const float*)d_in[0];
    const float* k = (const float*)d_in[1];
    const float* v = (const float*)d_in[2];
    float* out = (float*)d_out;
    unsigned short* kws  = (unsigned short*)d_ws;
    unsigned short* vtws = kws + (size_t)64 * S_LEN * DIM;
    cvt_k<<<dim3(64 * S_LEN * 8 / 256), 256, 0, stream>>>(k, kws);
    cvt_v<<<dim3(64 * (S_LEN / 64)), 256, 0, stream>>>(v, vtws);
    attn_fwd<<<dim3(1024), 256, 0, stream>>>(q, kws, vtws, out);
}

// Round 8
// 133.285 us; speedup vs baseline: 2.0565x; 2.0565x over previous
//
#include <hip/hip_runtime.h>
#include <stdint.h>
#include <math.h>

#define S_LEN 2048
#define DIM   64
#define QBLK  128
#define KVBLK 64
#define NKV   (S_LEN / KVBLK)   // 32

typedef __attribute__((ext_vector_type(8))) short short8;
typedef __attribute__((ext_vector_type(4))) float f32x4;

// fp32 -> bf16 round-to-nearest-even (cold paths only)
static __device__ __forceinline__ unsigned short f2bf(float f) {
    union { float f; uint32_t u; } cv; cv.f = f;
    uint32_t u = cv.u;
    return (unsigned short)((u + 0x7fffu + ((u >> 16) & 1u)) >> 16);
}

// async global->LDS, 16B per lane, LDS dest = wave-uniform base + lane*16
static __device__ __forceinline__ void gload16(const void* g, void* l) {
    __builtin_amdgcn_global_load_lds(
        (const __attribute__((address_space(1))) unsigned int*)g,
        (__attribute__((address_space(3))) unsigned int*)l, 16, 0, 0);
}

static __device__ __forceinline__ float vmax3(float a, float b, float c) {
    float d;
    asm("v_max3_f32 %0, %1, %2, %3" : "=v"(d) : "v"(a), "v"(b), "v"(c));
    return d;
}

// ---------------- pre-kernel 1: K fp32 -> bf16, per-row 16B-chunk XOR swizzle ----------------
__global__ void cvt_k(const float* __restrict__ kp, unsigned short* __restrict__ kws) {
    const int idx = blockIdx.x * 256 + threadIdx.x;
    const int c   = idx & 7;
    const int s   = (idx >> 3) & (S_LEN - 1);
    const int bh  = idx >> 14;
    const float* src = kp + ((size_t)bh * S_LEN + s) * DIM + c * 8;
    const f32x4 a = *reinterpret_cast<const f32x4*>(src);
    const f32x4 b = *reinterpret_cast<const f32x4*>(src + 4);
    short8 t;
    t[0] = (short)f2bf(a[0]); t[1] = (short)f2bf(a[1]);
    t[2] = (short)f2bf(a[2]); t[3] = (short)f2bf(a[3]);
    t[4] = (short)f2bf(b[0]); t[5] = (short)f2bf(b[1]);
    t[6] = (short)f2bf(b[2]); t[7] = (short)f2bf(b[3]);
    unsigned short* dst = kws + ((size_t)bh * S_LEN + s) * DIM + (size_t)((c ^ (s & 7)) * 8);
    *reinterpret_cast<short8*>(dst) = t;
}

// ---------------- pre-kernel 2: V fp32 -> bf16 transposed [d][key-position], kappa-permuted ----
// Position p holds key kappa(p) = 32*p5 + 8*p4 + 4*p3 + 16*p2 + 2*p1 + p0, so the PV B-frag
// (lane-local, phi-mapped P) and A-frag (V^T) agree on key order. Chunk-XOR-swizzled like K.
__global__ void cvt_v(const float* __restrict__ vp, unsigned short* __restrict__ vtws) {
    const int bh = blockIdx.x >> 5;
    const int t  = blockIdx.x & 31;
    const int tid = threadIdx.x;
    __shared__ unsigned short ldsT[DIM][72];   // [d][local key]

    const int i = tid >> 2;
    const int dbase = (tid & 3) * 16;
    const float* src = vp + ((size_t)bh * S_LEN + t * 64 + i) * DIM + dbase;
#pragma unroll
    for (int q4 = 0; q4 < 4; ++q4) {
        const f32x4 a = *reinterpret_cast<const f32x4*>(src + q4 * 4);
#pragma unroll
        for (int j = 0; j < 4; ++j) ldsT[dbase + q4 * 4 + j][i] = f2bf(a[j]);
    }
    __syncthreads();
#pragma unroll
    for (int hh = 0; hh < 2; ++hh) {
        const int slot = tid + hh * 256;
        const int d = slot >> 3, c_st = slot & 7;
        const int cl = c_st ^ (d & 7);
        short8 t8;
#pragma unroll
        for (int j = 0; j < 8; ++j) {
            const int p = cl * 8 + j;
            const int kap = (p & 32) | ((p & 16) >> 1) | ((p & 8) >> 1) | ((p & 4) << 2) | (p & 3);
            t8[j] = (short)ldsT[d][kap];
        }
        unsigned short* dst = vtws + ((size_t)bh * DIM + d) * S_LEN + t * 64 + c_st * 8;
        *reinterpret_cast<short8*>(dst) = t8;
    }
}

// ---- pipeline phases as macros on directly-named locals: nothing address-taken, all static ----
#define QK_TILE(ST, KL)                                                                              \
    do {                                                                                             \
        __builtin_amdgcn_s_setprio(1);                                                               \
        _Pragma("unroll")                                                                            \
        for (int nt = 0; nt < 4; ++nt) {                                                             \
            const short8 kf0 = *reinterpret_cast<const short8*>((KL) + off[nt][0]);                  \
            const short8 kf1 = *reinterpret_cast<const short8*>((KL) + off[nt][1]);                  \
            ST[0][nt] = __builtin_amdgcn_mfma_f32_16x16x32_bf16(kf0, qfrag[0][0], z4, 0, 0, 0);      \
            ST[1][nt] = __builtin_amdgcn_mfma_f32_16x16x32_bf16(kf0, qfrag[1][0], z4, 0, 0, 0);      \
            ST[0][nt] = __builtin_amdgcn_mfma_f32_16x16x32_bf16(kf1, qfrag[0][1], ST[0][nt], 0, 0, 0);\
            ST[1][nt] = __builtin_amdgcn_mfma_f32_16x16x32_bf16(kf1, qfrag[1][1], ST[1][nt], 0, 0, 0);\
        }                                                                                            \
        __builtin_amdgcn_s_setprio(0);                                                               \
    } while (0)

#define SMPV(ST, VL)                                                                                 \
    do {                                                                                             \
        _Pragma("unroll")                                                                            \
        for (int mt = 0; mt < 2; ++mt) {                                                             \
            const f32x4 s0 = ST[mt][0], s1 = ST[mt][1], s2 = ST[mt][2], s3 = ST[mt][3];              \
            const float a0 = vmax3(s0[0], s0[1], s0[2]);                                             \
            const float a1 = vmax3(s0[3], s1[0], s1[1]);                                             \
            const float a2 = vmax3(s1[2], s1[3], s2[0]);                                             \
            const float a3 = vmax3(s2[1], s2[2], s2[3]);                                             \
            const float a4 = vmax3(s3[0], s3[1], s3[2]);                                             \
            const float lane_mx = fmaxf(vmax3(a0, a1, a2), vmax3(a3, a4, s3[3]));                    \
            if (__any(lane_mx > m_run[mt] + 8.0f)) {                                                 \
                float mx = fmaxf(lane_mx, __shfl_xor(lane_mx, 16));                                  \
                mx = fmaxf(mx, __shfl_xor(mx, 32));                                                  \
                const float mnew = fmaxf(m_run[mt], mx);                                             \
                const float al = __builtin_amdgcn_exp2f(m_run[mt] - mnew);                           \
                m_run[mt] = mnew;                                                                    \
                l_part[mt] *= al;                                                                    \
                _Pragma("unroll")                                                                    \
                for (int nt = 0; nt < 4; ++nt) {                                                     \
                    f32x4 sc = o[mt][nt];                                                            \
                    sc[0] *= al; sc[1] *= al; sc[2] *= al; sc[3] *= al;                              \
                    o[mt][nt] = sc;                                                                  \
                }                                                                                    \
            }                                                                                        \
            const float mnow = m_run[mt];                                                            \
            f32x4 p0v, p1v, p2v, p3v;                                                                \
            p0v[0] = __builtin_amdgcn_exp2f(ST[mt][0][0] - mnow);                                    \
            p0v[1] = __builtin_amdgcn_exp2f(ST[mt][0][1] - mnow);                                    \
            p0v[2] = __builtin_amdgcn_exp2f(ST[mt][0][2] - mnow);                                    \
            p0v[3] = __builtin_amdgcn_exp2f(ST[mt][0][3] - mnow);                                    \
            p1v[0] = __builtin_amdgcn_exp2f(ST[mt][1][0] - mnow);                                    \
            p1v[1] = __builtin_amdgcn_exp2f(ST[mt][1][1] - mnow);                                    \
            p1v[2] = __builtin_amdgcn_exp2f(ST[mt][1][2] - mnow);                                    \
            p1v[3] = __builtin_amdgcn_exp2f(ST[mt][1][3] - mnow);                                    \
            p2v[0] = __builtin_amdgcn_exp2f(ST[mt][2][0] - mnow);                                    \
            p2v[1] = __builtin_amdgcn_exp2f(ST[mt][2][1] - mnow);                                    \
            p2v[2] = __builtin_amdgcn_exp2f(ST[mt][2][2] - mnow);                                    \
            p2v[3] = __builtin_amdgcn_exp2f(ST[mt][2][3] - mnow);                                    \
            p3v[0] = __builtin_amdgcn_exp2f(ST[mt][3][0] - mnow);                                    \
            p3v[1] = __builtin_amdgcn_exp2f(ST[mt][3][1] - mnow);                                    \
            p3v[2] = __builtin_amdgcn_exp2f(ST[mt][3][2] - mnow);                                    \
            p3v[3] = __builtin_amdgcn_exp2f(ST[mt][3][3] - mnow);                                    \
            l_part[mt] += ((p0v[0] + p0v[1]) + (p0v[2] + p0v[3]))                                    \
                        + ((p1v[0] + p1v[1]) + (p1v[2] + p1v[3]))                                    \
                        + ((p2v[0] + p2v[1]) + (p2v[2] + p2v[3]))                                    \
                        + ((p3v[0] + p3v[1]) + (p3v[2] + p3v[3]));                                   \
            short8 pfrag0, pfrag1;                                                                   \
            {                                                                                        \
                union { uint32_t u[4]; short8 v; } fr;                                               \
                asm("v_cvt_pk_bf16_f32 %0, %1, %2" : "=v"(fr.u[0]) : "v"(p0v[0]), "v"(p0v[1]));      \
                asm("v_cvt_pk_bf16_f32 %0, %1, %2" : "=v"(fr.u[1]) : "v"(p0v[2]), "v"(p0v[3]));      \
                asm("v_cvt_pk_bf16_f32 %0, %1, %2" : "=v"(fr.u[2]) : "v"(p1v[0]), "v"(p1v[1]));      \
                asm("v_cvt_pk_bf16_f32 %0, %1, %2" : "=v"(fr.u[3]) : "v"(p1v[2]), "v"(p1v[3]));      \
                pfrag0 = fr.v;                                                                       \
            }                                                                                        \
            {                                                                                        \
                union { uint32_t u[4]; short8 v; } fr;                                               \
                asm("v_cvt_pk_bf16_f32 %0, %1, %2" : "=v"(fr.u[0]) : "v"(p2v[0]), "v"(p2v[1]));      \
                asm("v_cvt_pk_bf16_f32 %0, %1, %2" : "=v"(fr.u[1]) : "v"(p2v[2]), "v"(p2v[3]));      \
                asm("v_cvt_pk_bf16_f32 %0, %1, %2" : "=v"(fr.u[2]) : "v"(p3v[0]), "v"(p3v[1]));      \
                asm("v_cvt_pk_bf16_f32 %0, %1, %2" : "=v"(fr.u[3]) : "v"(p3v[2]), "v"(p3v[3]));      \
                pfrag1 = fr.v;                                                                       \
            }                                                                                        \
            __builtin_amdgcn_s_setprio(1);                                                           \
            _Pragma("unroll")                                                                        \
            for (int ntd = 0; ntd < 4; ++ntd) {                                                      \
                const short8 vf0 = *reinterpret_cast<const short8*>((VL) + off[ntd][0]);             \
                const short8 vf1 = *reinterpret_cast<const short8*>((VL) + off[ntd][1]);             \
                o[mt][ntd] = __builtin_amdgcn_mfma_f32_16x16x32_bf16(vf0, pfrag0, o[mt][ntd], 0, 0, 0);\
                o[mt][ntd] = __builtin_amdgcn_mfma_f32_16x16x32_bf16(vf1, pfrag1, o[mt][ntd], 0, 0, 0);\
            }                                                                                        \
            __builtin_amdgcn_s_setprio(0);                                                           \
        }                                                                                            \
    } while (0)

// ---------------- main attention kernel: pipeline QK(t) || SM(t-1)+PV(t-1) ----------------
__global__ __launch_bounds__(256, 3)
void attn_fwd(const float* __restrict__ qp, const unsigned short* __restrict__ kws,
              const unsigned short* __restrict__ vtws, float* __restrict__ op) {
    const int lb = (blockIdx.x & 7) * 128 + (blockIdx.x >> 3);   // XCD swizzle (bijective)
    const int bh = lb >> 4;
    const int qb = lb & 15;
    const int tid  = threadIdx.x;
    const int wave = tid >> 6;
    const int lane = tid & 63;
    const int g = lane >> 4;
    const int r = lane & 15;

    __shared__ unsigned short klds[2][KVBLK * DIM];   // [key][chunk-swz] 8KB x2
    __shared__ unsigned short vlds[2][DIM * KVBLK];   // [d][pos-swz]     8KB x2

    const float*          qg    = qp   + (size_t)bh * (S_LEN * DIM);
    const unsigned short* kbase = kws  + (size_t)bh * (S_LEN * DIM);
    const unsigned short* vbase = vtws + (size_t)bh * (S_LEN * DIM);
    float*                og    = op   + (size_t)bh * (S_LEN * DIM);

    // Q frags (B-operand: col=q=lane&15, k=8g+i), pre-scaled by 0.125*log2(e) (base-2 scores)
    const float qscale = 0.125f * 1.44269504088896340736f;
    const int q0 = qb * QBLK + wave * 32;
    short8 qfrag[2][2];
#pragma unroll
    for (int mt = 0; mt < 2; ++mt) {
        const float* qrow = qg + (size_t)(q0 + mt * 16 + r) * DIM;
#pragma unroll
        for (int ks = 0; ks < 2; ++ks) {
            const f32x4 a = *reinterpret_cast<const f32x4*>(qrow + ks * 32 + 8 * g);
            const f32x4 b = *reinterpret_cast<const f32x4*>(qrow + ks * 32 + 8 * g + 4);
            short8 t;
            t[0] = (short)f2bf(a[0] * qscale); t[1] = (short)f2bf(a[1] * qscale);
            t[2] = (short)f2bf(a[2] * qscale); t[3] = (short)f2bf(a[3] * qscale);
            t[4] = (short)f2bf(b[0] * qscale); t[5] = (short)f2bf(b[1] * qscale);
            t[6] = (short)f2bf(b[2] * qscale); t[7] = (short)f2bf(b[3] * qscale);
            qfrag[mt][ks] = t;
        }
    }

    // hoisted LDS fragment offsets (identical formula for klds and vlds)
    int off[4][2];
#pragma unroll
    for (int nt = 0; nt < 4; ++nt)
#pragma unroll
        for (int ks = 0; ks < 2; ++ks)
            off[nt][ks] = (nt * 16 + r) * DIM + (((ks << 2) | g) ^ (r & 7)) * 8;

    // O^T accumulators + lane-uniform m,l per mt
    f32x4 o[2][4];
    float m_run[2], l_part[2];
#pragma unroll
    for (int mt = 0; mt < 2; ++mt) {
#pragma unroll
        for (int nt = 0; nt < 4; ++nt) { f32x4 z = {0.f, 0.f, 0.f, 0.f}; o[mt][nt] = z; }
        m_run[mt] = -INFINITY; l_part[mt] = 0.0f;
    }

    const int srow = lane >> 3, schk = lane & 7;
    auto stageK = [&](int t, int buf) {
        const int kv0 = t * KVBLK;
#pragma unroll
        for (int h = 0; h < 2; ++h) {
            const int row = wave * 16 + h * 8;
            gload16(kbase + (size_t)(kv0 + row + srow) * DIM + schk * 8,
                    &klds[buf][row * DIM]);
        }
    };
    auto stageV = [&](int t, int buf) {
        const int kv0 = t * KVBLK;
#pragma unroll
        for (int h = 0; h < 2; ++h) {
            const int row = wave * 16 + h * 8;
            gload16(vbase + (size_t)(row + srow) * S_LEN + kv0 + schk * 8,
                    &vlds[buf][row * DIM]);
        }
    };

    const f32x4 z4 = {0.f, 0.f, 0.f, 0.f};

    // score double-state: even tiles -> stA, odd tiles -> stB (directly named, static indices)
    f32x4 stA[2][4], stB[2][4];

    // ---- prologue: K(0),V(0) -> buf0; QK(0)->stA; K(1) in flight ----
    stageK(0, 0); stageV(0, 0);
    __syncthreads();
    stageK(1, 1);
    QK_TILE(stA, &klds[0][0]);
    __syncthreads();   // drains K(1)

    // ---- main loop, 2-unrolled: QK(t) || SM+PV(t-1) ----
    for (int tt = 1; tt < NKV; tt += 2) {
        {   // t = tt (odd): K(t) in klds[1]; V(t-1) in vlds[0]
            const int t = tt;
            if (t + 1 < NKV) stageK(t + 1, 0);   // overwrites K(t-1): QK(t-1) done pre-barrier
            stageV(t, 1);                        // overwrites V(t-2): PV(t-2) done pre-barrier
            QK_TILE(stB, &klds[1][0]);           // MFMA, independent of stA
            SMPV(stA, &vlds[0][0]);              // SM(t-1) VALU overlaps QK; PV(t-1)
            __syncthreads();                     // drains stages; frees vlds[0], klds[1]
        }
        if (tt + 1 < NKV) {   // t = tt+1 (even): K(t) in klds[0]; V(t-1) in vlds[1]
            const int t = tt + 1;
            stageK(t + 1, 1);                    // t+1 <= NKV-1 here
            stageV(t, 0);
            QK_TILE(stA, &klds[0][0]);
            SMPV(stB, &vlds[1][0]);
            __syncthreads();
        }
    }
    // ---- epilogue: last tile NKV-1 (odd) -> stB, V(NKV-1) in vlds[1] ----
    SMPV(stB, &vlds[1][0]);

#pragma unroll
    for (int mt = 0; mt < 2; ++mt) {
        float lfull = l_part[mt];
        lfull += __shfl_xor(lfull, 16);
        lfull += __shfl_xor(lfull, 32);
        const float inv = 1.0f / lfull;
        float* dst = og + (size_t)(q0 + mt * 16 + r) * DIM + 4 * g;
#pragma unroll
        for (int ntd = 0; ntd < 4; ++ntd) {
            f32x4 tt = o[mt][ntd];
            tt[0] *= inv; tt[1] *= inv; tt[2] *= inv; tt[3] *= inv;
            *reinterpret_cast<f32x4*>(dst + ntd * 16) = tt;
        }
    }
}

extern "C" void kernel_launch(void* const* d_in, const int* in_sizes, int n_in,
                              void* d_out, int out_size, void* d_ws, size_t ws_size,
                              hipStream_t stream) {
    const float* q = (const float*)d_in[0];
    const float* k = (const float*)d_in[1];
    const float* v = (const float*)d_in[2];
    float* out = (float*)d_out;
    unsigned short* kws  = (unsigned short*)d_ws;
    unsigned short* vtws = kws + (size_t)64 * S_LEN * DIM;
    cvt_k<<<dim3(64 * S_LEN * 8 / 256), 256, 0, stream>>>(k, kws);
    cvt_v<<<dim3(64 * (S_LEN / 64)), 256, 0, stream>>>(v, vtws);
    attn_fwd<<<dim3(1024), 256, 0, stream>>>(q, kws, vtws, out);
}

// Round 10
// 124.738 us; speedup vs baseline: 2.1974x; 1.0685x over previous
//
#include <hip/hip_runtime.h>
#include <stdint.h>
#include <math.h>

#define S_LEN 2048
#define DIM   64
#define QBLK  64
#define KVBLK 32
#define NKV   (S_LEN / KVBLK)   // 64
#define VSTR  40                 // V LDS row stride in u16 (80B): conflict-free quads (5d+g mod 8)

typedef __attribute__((ext_vector_type(8))) short short8;
typedef __attribute__((ext_vector_type(4))) float f32x4;

// fp32 -> bf16 round-to-nearest-even (cold paths only)
static __device__ __forceinline__ unsigned short f2bf(float f) {
    union { float f; uint32_t u; } cv; cv.f = f;
    uint32_t u = cv.u;
    return (unsigned short)((u + 0x7fffu + ((u >> 16) & 1u)) >> 16);
}

// async global->LDS, 16B per lane, LDS dest = wave-uniform base + lane*16
static __device__ __forceinline__ void gload16(const void* g, void* l) {
    __builtin_amdgcn_global_load_lds(
        (const __attribute__((address_space(1))) unsigned int*)g,
        (__attribute__((address_space(3))) unsigned int*)l, 16, 0, 0);
}

static __device__ __forceinline__ float vmax3(float a, float b, float c) {
    float d;
    asm("v_max3_f32 %0, %1, %2, %3" : "=v"(d) : "v"(a), "v"(b), "v"(c));
    return d;
}

// ---------------- pre-kernel 1 (UNCHANGED): K fp32 -> bf16, chunk XOR swizzle ----------------
__global__ void cvt_k(const float* __restrict__ kp, unsigned short* __restrict__ kws) {
    const int idx = blockIdx.x * 256 + threadIdx.x;
    const int c   = idx & 7;
    const int s   = (idx >> 3) & (S_LEN - 1);
    const int bh  = idx >> 14;
    const float* src = kp + ((size_t)bh * S_LEN + s) * DIM + c * 8;
    const f32x4 a = *reinterpret_cast<const f32x4*>(src);
    const f32x4 b = *reinterpret_cast<const f32x4*>(src + 4);
    short8 t;
    t[0] = (short)f2bf(a[0]); t[1] = (short)f2bf(a[1]);
    t[2] = (short)f2bf(a[2]); t[3] = (short)f2bf(a[3]);
    t[4] = (short)f2bf(b[0]); t[5] = (short)f2bf(b[1]);
    t[6] = (short)f2bf(b[2]); t[7] = (short)f2bf(b[3]);
    unsigned short* dst = kws + ((size_t)bh * S_LEN + s) * DIM + (size_t)((c ^ (s & 7)) * 8);
    *reinterpret_cast<short8*>(dst) = t;
}

// ---------------- pre-kernel 2 (UNCHANGED): V^T [d][pos], kappa64-permuted, chunk-swizzled ----
__global__ void cvt_v(const float* __restrict__ vp, unsigned short* __restrict__ vtws) {
    const int bh = blockIdx.x >> 5;
    const int t  = blockIdx.x & 31;
    const int tid = threadIdx.x;
    __shared__ unsigned short ldsT[DIM][72];   // [d][local key]

    const int i = tid >> 2;
    const int dbase = (tid & 3) * 16;
    const float* src = vp + ((size_t)bh * S_LEN + t * 64 + i) * DIM + dbase;
#pragma unroll
    for (int q4 = 0; q4 < 4; ++q4) {
        const f32x4 a = *reinterpret_cast<const f32x4*>(src + q4 * 4);
#pragma unroll
        for (int j = 0; j < 4; ++j) ldsT[dbase + q4 * 4 + j][i] = f2bf(a[j]);
    }
    __syncthreads();
#pragma unroll
    for (int hh = 0; hh < 2; ++hh) {
        const int slot = tid + hh * 256;
        const int d = slot >> 3, c_st = slot & 7;
        const int cl = c_st ^ (d & 7);
        short8 t8;
#pragma unroll
        for (int j = 0; j < 8; ++j) {
            const int p = cl * 8 + j;
            const int kap = (p & 32) | ((p & 16) >> 1) | ((p & 8) >> 1) | ((p & 4) << 2) | (p & 3);
            t8[j] = (short)ldsT[d][kap];
        }
        unsigned short* dst = vtws + ((size_t)bh * DIM + d) * S_LEN + t * 64 + c_st * 8;
        *reinterpret_cast<short8*>(dst) = t8;
    }
}

// ---------------- main attention kernel: 8 blocks/CU, QBLK=64, KVBLK=32 ----------------
__global__ __launch_bounds__(256, 8)
void attn_fwd(const float* __restrict__ qp, const unsigned short* __restrict__ kws,
              const unsigned short* __restrict__ vtws, float* __restrict__ op) {
    const int lb = (blockIdx.x & 7) * 256 + (blockIdx.x >> 3);   // XCD swizzle (bijective, 2048 blocks)
    const int bh = lb >> 5;
    const int qb = lb & 31;
    const int tid  = threadIdx.x;
    const int wave = tid >> 6;
    const int lane = tid & 63;
    const int g = lane >> 4;
    const int r = lane & 15;

    __shared__ unsigned short klds[2][KVBLK * DIM];   // 2 x 4KB, linear (gload_lds)
    __shared__ unsigned short vlds[2][DIM * VSTR];    // 2 x 5KB, stride-80B padded (reg-staged)

    const float*          qg    = qp   + (size_t)bh * (S_LEN * DIM);
    const unsigned short* kbase = kws  + (size_t)bh * (S_LEN * DIM);
    const unsigned short* vbase = vtws + (size_t)bh * (S_LEN * DIM);
    float*                og    = op   + (size_t)bh * (S_LEN * DIM);

    // Q frags (B-operand: col=q=lane&15, k=8g+i), pre-scaled by 0.125*log2(e) (base-2 scores)
    const float qscale = 0.125f * 1.44269504088896340736f;
    const int q0 = qb * QBLK + wave * 16;
    short8 qfrag[2];
    {
        const float* qrow = qg + (size_t)(q0 + r) * DIM;
#pragma unroll
        for (int ks = 0; ks < 2; ++ks) {
            const f32x4 a = *reinterpret_cast<const f32x4*>(qrow + ks * 32 + 8 * g);
            const f32x4 b = *reinterpret_cast<const f32x4*>(qrow + ks * 32 + 8 * g + 4);
            short8 t;
            t[0] = (short)f2bf(a[0] * qscale); t[1] = (short)f2bf(a[1] * qscale);
            t[2] = (short)f2bf(a[2] * qscale); t[3] = (short)f2bf(a[3] * qscale);
            t[4] = (short)f2bf(b[0] * qscale); t[5] = (short)f2bf(b[1] * qscale);
            t[6] = (short)f2bf(b[2] * qscale); t[7] = (short)f2bf(b[3] * qscale);
            qfrag[ks] = t;
        }
    }

    // O^T accumulators: o[ntd][rg] = O^T[d=ntd*16+4g+rg][q=r]; lane-uniform m,l
    f32x4 o[4];
#pragma unroll
    for (int nt = 0; nt < 4; ++nt) { f32x4 z = {0.f, 0.f, 0.f, 0.f}; o[nt] = z; }
    float m_run = -INFINITY, l_part = 0.0f;

    // K staging: 1 gload16 per wave per tile (rows wave*8 .. wave*8+7)
    const int srow = lane >> 3, schk = lane & 7;
    auto stageK = [&](int t, int buf) {
        gload16(kbase + (size_t)(t * KVBLK + wave * 8 + srow) * DIM + schk * 8,
                &klds[buf][(wave * 8) * DIM]);
    };
    // V staging: thread (vd, vc) loads logical chunk (4h+vc) of V^T row vd, tile t>>1 (h=t&1).
    // Tile stride per d-row is 64 u16 (cvt_v layout: t*64 + c_st*8).  [R9 bug: was *128]
    const int vd = tid >> 2, vc = tid & 3;
    auto loadV = [&](int t) {
        const int sc = ((4 * (t & 1) + vc) ^ (vd & 7));   // undo cvt_v chunk swizzle
        return *reinterpret_cast<const short8*>(
            vbase + (size_t)vd * S_LEN + (t >> 1) * 64 + sc * 8);
    };
    const int vwoff = vd * VSTR + vc * 8;   // LDS write slot (stride-80B row)

    // hoisted LDS read offsets
    int koff[2][2], voff[4];
#pragma unroll
    for (int nt = 0; nt < 2; ++nt)
#pragma unroll
        for (int ks = 0; ks < 2; ++ks)
            koff[nt][ks] = (nt * 16 + r) * DIM + (((ks << 2) | g) ^ (r & 7)) * 8;
#pragma unroll
    for (int nt = 0; nt < 4; ++nt) voff[nt] = (nt * 16 + r) * VSTR + g * 8;

    const f32x4 z4 = {0.f, 0.f, 0.f, 0.f};

    // ---- prologue: K(0) async; V(0) via regs ----
    stageK(0, 0);
    {
        short8 v0 = loadV(0);
        *reinterpret_cast<short8*>(&vlds[0][vwoff]) = v0;
    }
    __syncthreads();
    int cur = 0;

    for (int t = 0; t < NKV; ++t) {
        short8 vnext;
        if (t + 1 < NKV) {
            stageK(t + 1, cur ^ 1);       // async K prefetch (drains at end barrier)
            vnext = loadV(t + 1);          // V prefetch into regs (T14 issue-early)
        }

        // ---- S^T = K Q^T : st[nt][rg] = S[key=nt*16+4g+rg][q=r] (base-2 domain) ----
        const unsigned short* kl = &klds[cur][0];
        __builtin_amdgcn_s_setprio(1);
        const short8 kf00 = *reinterpret_cast<const short8*>(kl + koff[0][0]);
        const short8 kf01 = *reinterpret_cast<const short8*>(kl + koff[0][1]);
        const short8 kf10 = *reinterpret_cast<const short8*>(kl + koff[1][0]);
        const short8 kf11 = *reinterpret_cast<const short8*>(kl + koff[1][1]);
        f32x4 st0 = __builtin_amdgcn_mfma_f32_16x16x32_bf16(kf00, qfrag[0], z4, 0, 0, 0);
        f32x4 st1 = __builtin_amdgcn_mfma_f32_16x16x32_bf16(kf10, qfrag[0], z4, 0, 0, 0);
        st0 = __builtin_amdgcn_mfma_f32_16x16x32_bf16(kf01, qfrag[1], st0, 0, 0, 0);
        st1 = __builtin_amdgcn_mfma_f32_16x16x32_bf16(kf11, qfrag[1], st1, 0, 0, 0);
        __builtin_amdgcn_s_setprio(0);

        // ---- in-register online softmax (defer-max THR=8); 8 scores/lane ----
        const float a0 = vmax3(st0[0], st0[1], st0[2]);
        const float a1 = vmax3(st0[3], st1[0], st1[1]);
        const float a2 = fmaxf(st1[2], st1[3]);
        const float lane_mx = vmax3(a0, a1, a2);
        if (__any(lane_mx > m_run + 8.0f)) {
            float mx = fmaxf(lane_mx, __shfl_xor(lane_mx, 16));
            mx = fmaxf(mx, __shfl_xor(mx, 32));
            const float mnew = fmaxf(m_run, mx);
            const float al = __builtin_amdgcn_exp2f(m_run - mnew);   // -inf -> 0 on first tile
            m_run = mnew;
            l_part *= al;
#pragma unroll
            for (int nt = 0; nt < 4; ++nt) {
                f32x4 sc = o[nt];
                sc[0] *= al; sc[1] *= al; sc[2] *= al; sc[3] *= al;
                o[nt] = sc;
            }
        }
        f32x4 p0, p1;
        p0[0] = __builtin_amdgcn_exp2f(st0[0] - m_run);
        p0[1] = __builtin_amdgcn_exp2f(st0[1] - m_run);
        p0[2] = __builtin_amdgcn_exp2f(st0[2] - m_run);
        p0[3] = __builtin_amdgcn_exp2f(st0[3] - m_run);
        p1[0] = __builtin_amdgcn_exp2f(st1[0] - m_run);
        p1[1] = __builtin_amdgcn_exp2f(st1[1] - m_run);
        p1[2] = __builtin_amdgcn_exp2f(st1[2] - m_run);
        p1[3] = __builtin_amdgcn_exp2f(st1[3] - m_run);
        l_part += ((p0[0] + p0[1]) + (p0[2] + p0[3])) + ((p1[0] + p1[1]) + (p1[2] + p1[3]));

        // pfrag slot i = P[key = 16*(i>>2) + 4g + (i&3)]  (phi32; kappa64 bit5 pass-through)
        short8 pfrag;
        {
            union { uint32_t u[4]; short8 v; } fr;
            asm("v_cvt_pk_bf16_f32 %0, %1, %2" : "=v"(fr.u[0]) : "v"(p0[0]), "v"(p0[1]));
            asm("v_cvt_pk_bf16_f32 %0, %1, %2" : "=v"(fr.u[1]) : "v"(p0[2]), "v"(p0[3]));
            asm("v_cvt_pk_bf16_f32 %0, %1, %2" : "=v"(fr.u[2]) : "v"(p1[0]), "v"(p1[1]));
            asm("v_cvt_pk_bf16_f32 %0, %1, %2" : "=v"(fr.u[3]) : "v"(p1[2]), "v"(p1[3]));
            pfrag = fr.v;
        }

        // ---- O^T += V^T P^T ----
        const unsigned short* vl = &vlds[cur][0];
        __builtin_amdgcn_s_setprio(1);
#pragma unroll
        for (int nt = 0; nt < 4; ++nt) {
            const short8 vf = *reinterpret_cast<const short8*>(vl + voff[nt]);
            o[nt] = __builtin_amdgcn_mfma_f32_16x16x32_bf16(vf, pfrag, o[nt], 0, 0, 0);
        }
        __builtin_amdgcn_s_setprio(0);

        // ---- write prefetched V into the buffer freed by the previous barrier ----
        if (t + 1 < NKV)
            *reinterpret_cast<short8*>(&vlds[cur ^ 1][vwoff]) = vnext;

        __syncthreads();   // K(t+1) landed; V(t+1) ds_write visible; all reads of cur done
        cur ^= 1;
    }

    // ---- epilogue: l reduce over lane-groups, O^T/l, float4 stores ----
    float lfull = l_part;
    lfull += __shfl_xor(lfull, 16);
    lfull += __shfl_xor(lfull, 32);
    const float inv = 1.0f / lfull;
    float* dst = og + (size_t)(q0 + r) * DIM + 4 * g;
#pragma unroll
    for (int nt = 0; nt < 4; ++nt) {
        f32x4 tt = o[nt];
        tt[0] *= inv; tt[1] *= inv; tt[2] *= inv; tt[3] *= inv;
        *reinterpret_cast<f32x4*>(dst + nt * 16) = tt;
    }
}

extern "C" void kernel_launch(void* const* d_in, const int* in_sizes, int n_in,
                              void* d_out, int out_size, void* d_ws, size_t ws_size,
                              hipStream_t stream) {
    const float* q = (const float*)d_in[0];
    const float* k = (const float*)d_in[1];
    const float* v = (const float*)d_in[2];
    float* out = (float*)d_out;
    unsigned short* kws  = (unsigned short*)d_ws;
    unsigned short* vtws = kws + (size_t)64 * S_LEN * DIM;
    cvt_k<<<dim3(64 * S_LEN * 8 / 256), 256, 0, stream>>>(k, kws);
    cvt_v<<<dim3(64 * (S_LEN / 64)), 256, 0, stream>>>(v, vtws);
    attn_fwd<<<dim3(2048), 256, 0, stream>>>(q, kws, vtws, out);
}

// Round 11
// 121.268 us; speedup vs baseline: 2.2603x; 1.0286x over previous
//
#include <hip/hip_runtime.h>
#include <stdint.h>
#include <math.h>

#define S_LEN 2048
#define DIM   64
#define QBLK  64
#define KVBLK 32
#define NKV   (S_LEN / KVBLK)   // 64

typedef __attribute__((ext_vector_type(8))) short short8;
typedef __attribute__((ext_vector_type(4))) float f32x4;

// fp32 -> bf16 round-to-nearest-even (cold paths only)
static __device__ __forceinline__ unsigned short f2bf(float f) {
    union { float f; uint32_t u; } cv; cv.f = f;
    uint32_t u = cv.u;
    return (unsigned short)((u + 0x7fffu + ((u >> 16) & 1u)) >> 16);
}

// async global->LDS, 16B per lane, LDS dest = wave-uniform base + lane*16
static __device__ __forceinline__ void gload16(const void* g, void* l) {
    __builtin_amdgcn_global_load_lds(
        (const __attribute__((address_space(1))) unsigned int*)g,
        (__attribute__((address_space(3))) unsigned int*)l, 16, 0, 0);
}

static __device__ __forceinline__ float vmax3(float a, float b, float c) {
    float d;
    asm("v_max3_f32 %0, %1, %2, %3" : "=v"(d) : "v"(a), "v"(b), "v"(c));
    return d;
}

// ---------------- pre-kernel 1 (UNCHANGED): K fp32 -> bf16, chunk XOR swizzle ----------------
__global__ void cvt_k(const float* __restrict__ kp, unsigned short* __restrict__ kws) {
    const int idx = blockIdx.x * 256 + threadIdx.x;
    const int c   = idx & 7;
    const int s   = (idx >> 3) & (S_LEN - 1);
    const int bh  = idx >> 14;
    const float* src = kp + ((size_t)bh * S_LEN + s) * DIM + c * 8;
    const f32x4 a = *reinterpret_cast<const f32x4*>(src);
    const f32x4 b = *reinterpret_cast<const f32x4*>(src + 4);
    short8 t;
    t[0] = (short)f2bf(a[0]); t[1] = (short)f2bf(a[1]);
    t[2] = (short)f2bf(a[2]); t[3] = (short)f2bf(a[3]);
    t[4] = (short)f2bf(b[0]); t[5] = (short)f2bf(b[1]);
    t[6] = (short)f2bf(b[2]); t[7] = (short)f2bf(b[3]);
    unsigned short* dst = kws + ((size_t)bh * S_LEN + s) * DIM + (size_t)((c ^ (s & 7)) * 8);
    *reinterpret_cast<short8*>(dst) = t;
}

// ---------------- pre-kernel 2 (NEW layout): V^T [d][key], 32-key halves, kappa32 in-half ----
// Row d (2048 u16) = 32 tiles x 2 halves x 4 stored chunks x 8 u16.
// Stored chunk c_st of half h of tile T holds logical chunk cl = c_st ^ ((d>>1)&3):
//   slot j -> key T*64 + h*32 + kappa32(cl*8+j),
//   kappa32(p) = ((p&4)<<2) | ((p&16)>>1) | ((p&8)>>1) | (p&3)   [= 16(i>>2)+4g+(i&3) at p=8g+i]
// Half-tiles are 64B-contiguous -> V stages via gload16 (no ds_write anywhere).
__global__ void cvt_v(const float* __restrict__ vp, unsigned short* __restrict__ vtws) {
    const int bh = blockIdx.x >> 5;
    const int T  = blockIdx.x & 31;
    const int tid = threadIdx.x;
    __shared__ unsigned short ldsT[DIM][72];   // [d][local key]

    const int i = tid >> 2;
    const int dbase = (tid & 3) * 16;
    const float* src = vp + ((size_t)bh * S_LEN + T * 64 + i) * DIM + dbase;
#pragma unroll
    for (int q4 = 0; q4 < 4; ++q4) {
        const f32x4 a = *reinterpret_cast<const f32x4*>(src + q4 * 4);
#pragma unroll
        for (int j = 0; j < 4; ++j) ldsT[dbase + q4 * 4 + j][i] = f2bf(a[j]);
    }
    __syncthreads();
#pragma unroll
    for (int hh = 0; hh < 2; ++hh) {
        const int slot = tid + hh * 256;          // 0..511 = (d, h, c_st)
        const int d = slot >> 3;
        const int h = (slot >> 2) & 1;
        const int c_st = slot & 3;
        const int cl = c_st ^ ((d >> 1) & 3);
        short8 t8;
#pragma unroll
        for (int j = 0; j < 8; ++j) {
            const int p = cl * 8 + j;
            const int kap = ((p & 4) << 2) | ((p & 16) >> 1) | ((p & 8) >> 1) | (p & 3);
            t8[j] = (short)ldsT[d][h * 32 + kap];
        }
        unsigned short* dst = vtws + ((size_t)bh * DIM + d) * S_LEN + T * 64 + h * 32 + c_st * 8;
        *reinterpret_cast<short8*>(dst) = t8;
    }
}

// ---------------- main attention kernel: 8 blocks/CU, QBLK=64, KVBLK=32, all-gload16 ----------------
__global__ __launch_bounds__(256, 8)
void attn_fwd(const float* __restrict__ qp, const unsigned short* __restrict__ kws,
              const unsigned short* __restrict__ vtws, float* __restrict__ op) {
    const int lb = (blockIdx.x & 7) * 256 + (blockIdx.x >> 3);   // XCD swizzle (bijective, 2048 blocks)
    const int bh = lb >> 5;
    const int qb = lb & 31;
    const int tid  = threadIdx.x;
    const int wave = tid >> 6;
    const int lane = tid & 63;
    const int g = lane >> 4;
    const int r = lane & 15;

    __shared__ unsigned short klds[2][KVBLK * DIM];   // 2 x 4KB, linear (gload16)
    __shared__ unsigned short vlds[2][DIM * 32];      // 2 x 4KB, 64B rows (gload16)

    const float*          qg    = qp   + (size_t)bh * (S_LEN * DIM);
    const unsigned short* kbase = kws  + (size_t)bh * (S_LEN * DIM);
    const unsigned short* vbase = vtws + (size_t)bh * (S_LEN * DIM);
    float*                og    = op   + (size_t)bh * (S_LEN * DIM);

    // Q frags (B-operand: col=q=lane&15, k=8g+i), pre-scaled by 0.125*log2(e) (base-2 scores)
    const float qscale = 0.125f * 1.44269504088896340736f;
    const int q0 = qb * QBLK + wave * 16;
    short8 qfrag[2];
    {
        const float* qrow = qg + (size_t)(q0 + r) * DIM;
#pragma unroll
        for (int ks = 0; ks < 2; ++ks) {
            const f32x4 a = *reinterpret_cast<const f32x4*>(qrow + ks * 32 + 8 * g);
            const f32x4 b = *reinterpret_cast<const f32x4*>(qrow + ks * 32 + 8 * g + 4);
            short8 t;
            t[0] = (short)f2bf(a[0] * qscale); t[1] = (short)f2bf(a[1] * qscale);
            t[2] = (short)f2bf(a[2] * qscale); t[3] = (short)f2bf(a[3] * qscale);
            t[4] = (short)f2bf(b[0] * qscale); t[5] = (short)f2bf(b[1] * qscale);
            t[6] = (short)f2bf(b[2] * qscale); t[7] = (short)f2bf(b[3] * qscale);
            qfrag[ks] = t;
        }
    }

    // O^T accumulators: o[ntd][rg] = O^T[d=ntd*16+4g+rg][q=r]; lane-uniform m,l
    f32x4 o[4];
#pragma unroll
    for (int nt = 0; nt < 4; ++nt) { f32x4 z = {0.f, 0.f, 0.f, 0.f}; o[nt] = z; }
    float m_run = -INFINITY, l_part = 0.0f;

    // K staging: 1 gload16 per wave per tile (rows wave*8 .. wave*8+7)
    const int srow = lane >> 3, schk = lane & 7;
    // V staging: 1 gload16 per wave per tile: lane l -> d = wave*16 + (l>>2), chunk c_st = l&3;
    // source half-tile (T = t>>1, h = t&1) is 64B-contiguous per d-row.
    const int vd = wave * 16 + ((lane >> 2) & 15), vcst = lane & 3;
    auto stage = [&](int t, int buf) {
        gload16(kbase + (size_t)(t * KVBLK + wave * 8 + srow) * DIM + schk * 8,
                &klds[buf][(wave * 8) * DIM]);
        gload16(vbase + (size_t)vd * S_LEN + (t >> 1) * 64 + (t & 1) * 32 + vcst * 8,
                &vlds[buf][wave * 512]);
    };

    // hoisted LDS read offsets
    int koff[2][2], voff[4];
#pragma unroll
    for (int nt = 0; nt < 2; ++nt)
#pragma unroll
        for (int ks = 0; ks < 2; ++ks)
            koff[nt][ks] = (nt * 16 + r) * DIM + (((ks << 2) | g) ^ (r & 7)) * 8;
#pragma unroll
    for (int nt = 0; nt < 4; ++nt)
        voff[nt] = (nt * 16 + r) * 32 + (g ^ ((r >> 1) & 3)) * 8;   // cl=g at stored g^((d>>1)&3)

    const f32x4 z4 = {0.f, 0.f, 0.f, 0.f};

    // ---- prologue ----
    stage(0, 0);
    __syncthreads();
    int cur = 0;

    for (int t = 0; t < NKV; ++t) {
        if (t + 1 < NKV) stage(t + 1, cur ^ 1);   // async K+V prefetch; drains at end barrier

        // ---- S^T = K Q^T : st[nt][rg] = S[key=nt*16+4g+rg][q=r] (base-2 domain) ----
        const unsigned short* kl = &klds[cur][0];
        __builtin_amdgcn_s_setprio(1);
        const short8 kf00 = *reinterpret_cast<const short8*>(kl + koff[0][0]);
        const short8 kf01 = *reinterpret_cast<const short8*>(kl + koff[0][1]);
        const short8 kf10 = *reinterpret_cast<const short8*>(kl + koff[1][0]);
        const short8 kf11 = *reinterpret_cast<const short8*>(kl + koff[1][1]);
        f32x4 st0 = __builtin_amdgcn_mfma_f32_16x16x32_bf16(kf00, qfrag[0], z4, 0, 0, 0);
        f32x4 st1 = __builtin_amdgcn_mfma_f32_16x16x32_bf16(kf10, qfrag[0], z4, 0, 0, 0);
        st0 = __builtin_amdgcn_mfma_f32_16x16x32_bf16(kf01, qfrag[1], st0, 0, 0, 0);
        st1 = __builtin_amdgcn_mfma_f32_16x16x32_bf16(kf11, qfrag[1], st1, 0, 0, 0);
        __builtin_amdgcn_s_setprio(0);

        // ---- in-register online softmax (defer-max THR=8); 8 scores/lane ----
        const float a0 = vmax3(st0[0], st0[1], st0[2]);
        const float a1 = vmax3(st0[3], st1[0], st1[1]);
        const float a2 = fmaxf(st1[2], st1[3]);
        const float lane_mx = vmax3(a0, a1, a2);
        if (__any(lane_mx > m_run + 8.0f)) {
            float mx = fmaxf(lane_mx, __shfl_xor(lane_mx, 16));
            mx = fmaxf(mx, __shfl_xor(mx, 32));
            const float mnew = fmaxf(m_run, mx);
            const float al = __builtin_amdgcn_exp2f(m_run - mnew);   // -inf -> 0 on first tile
            m_run = mnew;
            l_part *= al;
#pragma unroll
            for (int nt = 0; nt < 4; ++nt) {
                f32x4 sc = o[nt];
                sc[0] *= al; sc[1] *= al; sc[2] *= al; sc[3] *= al;
                o[nt] = sc;
            }
        }
        f32x4 p0, p1;
        p0[0] = __builtin_amdgcn_exp2f(st0[0] - m_run);
        p0[1] = __builtin_amdgcn_exp2f(st0[1] - m_run);
        p0[2] = __builtin_amdgcn_exp2f(st0[2] - m_run);
        p0[3] = __builtin_amdgcn_exp2f(st0[3] - m_run);
        p1[0] = __builtin_amdgcn_exp2f(st1[0] - m_run);
        p1[1] = __builtin_amdgcn_exp2f(st1[1] - m_run);
        p1[2] = __builtin_amdgcn_exp2f(st1[2] - m_run);
        p1[3] = __builtin_amdgcn_exp2f(st1[3] - m_run);
        l_part += ((p0[0] + p0[1]) + (p0[2] + p0[3])) + ((p1[0] + p1[1]) + (p1[2] + p1[3]));

        // pfrag slot i = P[key = 16*(i>>2) + 4g + (i&3)] = kappa32(8g+i)
        short8 pfrag;
        {
            union { uint32_t u[4]; short8 v; } fr;
            asm("v_cvt_pk_bf16_f32 %0, %1, %2" : "=v"(fr.u[0]) : "v"(p0[0]), "v"(p0[1]));
            asm("v_cvt_pk_bf16_f32 %0, %1, %2" : "=v"(fr.u[1]) : "v"(p0[2]), "v"(p0[3]));
            asm("v_cvt_pk_bf16_f32 %0, %1, %2" : "=v"(fr.u[2]) : "v"(p1[0]), "v"(p1[1]));
            asm("v_cvt_pk_bf16_f32 %0, %1, %2" : "=v"(fr.u[3]) : "v"(p1[2]), "v"(p1[3]));
            pfrag = fr.v;
        }

        // ---- O^T += V^T P^T ----
        const unsigned short* vl = &vlds[cur][0];
        __builtin_amdgcn_s_setprio(1);
#pragma unroll
        for (int nt = 0; nt < 4; ++nt) {
            const short8 vf = *reinterpret_cast<const short8*>(vl + voff[nt]);
            o[nt] = __builtin_amdgcn_mfma_f32_16x16x32_bf16(vf, pfrag, o[nt], 0, 0, 0);
        }
        __builtin_amdgcn_s_setprio(0);

        __syncthreads();   // K(t+1)/V(t+1) landed; all reads of cur done
        cur ^= 1;
    }

    // ---- epilogue: l reduce over lane-groups, O^T/l, float4 stores ----
    float lfull = l_part;
    lfull += __shfl_xor(lfull, 16);
    lfull += __shfl_xor(lfull, 32);
    const float inv = 1.0f / lfull;
    float* dst = og + (size_t)(q0 + r) * DIM + 4 * g;
#pragma unroll
    for (int nt = 0; nt < 4; ++nt) {
        f32x4 tt = o[nt];
        tt[0] *= inv; tt[1] *= inv; tt[2] *= inv; tt[3] *= inv;
        *reinterpret_cast<f32x4*>(dst + nt * 16) = tt;
    }
}

extern "C" void kernel_launch(void* const* d_in, const int* in_sizes, int n_in,
                              void* d_out, int out_size, void* d_ws, size_t ws_size,
                              hipStream_t stream) {
    const float* q = (const float*)d_in[0];
    const float* k = (const float*)d_in[1];
    const float* v = (const float*)d_in[2];
    float* out = (float*)d_out;
    unsigned short* kws  = (unsigned short*)d_ws;
    unsigned short* vtws = kws + (size_t)64 * S_LEN * DIM;
    cvt_k<<<dim3(64 * S_LEN * 8 / 256), 256, 0, stream>>>(k, kws);
    cvt_v<<<dim3(64 * (S_LEN / 64)), 256, 0, stream>>>(v, vtws);
    attn_fwd<<<dim3(2048), 256, 0, stream>>>(q, kws, vtws, out);
}